// Round 2
// baseline (1989.852 us; speedup 1.0000x reference)
//
#include <hip/hip_runtime.h>

// 2-layer GCN, restructured:
//   ag1[n]  = emb[x_ids[n]] * dinv[n]                       (16f)
//   s1[c]   = dinv[c] * (sum_{r->c} ag1[r] + ag1[c])        (16f)  [CSR gather]
//   y1g[n]  = relu(s1[n] @ W1 + b1) * dinv[n]               (32f)
//   s2[c]   = dinv[c] * (sum_{r->c} y1g[r] + y1g[c])        (32f)  [CSR gather]
//   P[g]    = sum_{batch[n]==g} s2[n]                       (atomic, 256x32)
//   out[g]  = P[g] @ W2 + cnt[g] * b2                       (256x41)
//
// CSR built via 2-level bucket sort (128-node buckets) to avoid the 16x
// write amplification of a flat random scatter (R1: k_fill 280us, 195MB
// WRITE_SIZE for 12.8MB of payload).

constexpr int BLK = 256;
constexpr int BKT_SHIFT = 7;            // 128 nodes per bucket
constexpr int BKT = 1 << BKT_SHIFT;
constexpr int MAXBKT = 1024;            // padded bucket-count array

__global__ __launch_bounds__(BLK) void k_bcount(const int* __restrict__ col, int E,
                                                int* __restrict__ bcnt) {
  int e = blockIdx.x * BLK + threadIdx.x;
  if (e < E) atomicAdd(&bcnt[col[e] >> BKT_SHIFT], 1);
}

// scan 1024 padded bucket counts in one block; init bucket_off + bcursor
__global__ __launch_bounds__(BLK) void k_bscan(const int* __restrict__ bcnt,
                                               int* __restrict__ bucket_off,
                                               int* __restrict__ bcursor) {
  __shared__ int sd[BLK];
  int tid = threadIdx.x;
  int idx = tid * 4;
  int4 v = *(const int4*)(bcnt + idx);
  int tsum = v.x + v.y + v.z + v.w;
  sd[tid] = tsum;
  __syncthreads();
  for (int off = 1; off < BLK; off <<= 1) {
    int u = (tid >= off) ? sd[tid - off] : 0;
    __syncthreads();
    sd[tid] += u;
    __syncthreads();
  }
  int run = sd[tid] - tsum;  // exclusive
  int o0 = run, o1 = run + v.x, o2 = o1 + v.y, o3 = o2 + v.z;
  bucket_off[idx + 0] = o0; bcursor[idx + 0] = o0;
  bucket_off[idx + 1] = o1; bcursor[idx + 1] = o1;
  bucket_off[idx + 2] = o2; bcursor[idx + 2] = o2;
  bucket_off[idx + 3] = o3; bcursor[idx + 3] = o3;
  if (tid == BLK - 1) bucket_off[MAXBKT] = sd[tid];
}

// scatter edges into bucket order; packed = (row << 7) | (col & 127)
__global__ __launch_bounds__(BLK) void k_bfill(const int* __restrict__ row,
                                               const int* __restrict__ col, int E,
                                               int* __restrict__ bcursor,
                                               int* __restrict__ bpacked) {
  int e = blockIdx.x * BLK + threadIdx.x;
  if (e < E) {
    int c = col[e];
    int p = atomicAdd(&bcursor[c >> BKT_SHIFT], 1);
    bpacked[p] = (row[e] << BKT_SHIFT) | (c & (BKT - 1));
  }
}

// per-bucket: LDS count -> LDS scan -> col_ptr/dinv/cursor -> localized fill
__global__ __launch_bounds__(BLK) void k_build(const int* __restrict__ bpacked,
                                               const int* __restrict__ bucket_off,
                                               int N, int E,
                                               int* __restrict__ col_ptr,
                                               float* __restrict__ dinv,
                                               int* __restrict__ edge_row) {
  __shared__ int cnt[BKT];
  __shared__ int sc[BKT];
  __shared__ int lcur[BKT];
  int tid = threadIdx.x;
  int b = blockIdx.x;
  int beg = bucket_off[b], end = bucket_off[b + 1];
  if (tid < BKT) cnt[tid] = 0;
  __syncthreads();
  for (int i = beg + tid; i < end; i += BLK)
    atomicAdd(&cnt[bpacked[i] & (BKT - 1)], 1);
  __syncthreads();
  if (tid < BKT) sc[tid] = cnt[tid];
  __syncthreads();
  for (int off = 1; off < BKT; off <<= 1) {
    int u = 0;
    if (tid < BKT && tid >= off) u = sc[tid - off];
    __syncthreads();
    if (tid < BKT) sc[tid] += u;
    __syncthreads();
  }
  if (tid < BKT) {
    int node = b * BKT + tid;
    if (node < N) {
      int excl = sc[tid] - cnt[tid];
      int pos = beg + excl;
      col_ptr[node] = pos;
      lcur[tid] = pos;
      dinv[node] = rsqrtf((float)(cnt[tid] + 1));  // +1 self-loop
    }
  }
  if (b == 0 && tid == 0) col_ptr[N] = E;
  __syncthreads();
  for (int i = beg + tid; i < end; i += BLK) {
    int p = bpacked[i];
    int pos = atomicAdd(&lcur[p & (BKT - 1)], 1);
    edge_row[pos] = p >> BKT_SHIFT;
  }
}

// ag1[n] = emb[x_ids[n]] * dinv[n]; also count nodes per graph
__global__ __launch_bounds__(BLK) void k_prep(const int* __restrict__ x_ids,
                                              const int* __restrict__ batch,
                                              const float* __restrict__ emb,
                                              const float* __restrict__ dinv, int N,
                                              float* __restrict__ ag1,
                                              int* __restrict__ cnt) {
  int t = blockIdx.x * BLK + threadIdx.x;
  int n = t >> 2, ch = t & 3;
  if (n >= N) return;
  float d = dinv[n];
  float4 v = *(const float4*)(emb + (size_t)x_ids[n] * 16 + ch * 4);
  v.x *= d; v.y *= d; v.z *= d; v.w *= d;
  *(float4*)(ag1 + (size_t)n * 16 + ch * 4) = v;
  if (ch == 0) atomicAdd(&cnt[batch[n]], 1);
}

// s1[c] = dinv[c] * (sum ag1[r] + ag1[c]); 4 lanes/node, float4 each
__global__ __launch_bounds__(BLK) void k_agg1(const float* __restrict__ ag1,
                                              const int* __restrict__ col_ptr,
                                              const int* __restrict__ edge_row,
                                              const float* __restrict__ dinv, int N,
                                              float* __restrict__ s1) {
  int t = blockIdx.x * BLK + threadIdx.x;
  int n = t >> 2, ch = t & 3;
  if (n >= N) return;
  int off = ch * 4;
  float4 acc = *(const float4*)(ag1 + (size_t)n * 16 + off);
  int beg = col_ptr[n], end = col_ptr[n + 1];
  for (int i = beg; i < end; ++i) {
    int r = edge_row[i];
    float4 v = *(const float4*)(ag1 + (size_t)r * 16 + off);
    acc.x += v.x; acc.y += v.y; acc.z += v.z; acc.w += v.w;
  }
  float d = dinv[n];
  acc.x *= d; acc.y *= d; acc.z *= d; acc.w *= d;
  *(float4*)(s1 + (size_t)n * 16 + off) = acc;
}

// y1g[n] = relu(s1[n] @ W1 + b1) * dinv[n]; 8 lanes/node, 4 outs each
__global__ __launch_bounds__(BLK) void k_t1(const float* __restrict__ s1,
                                            const float* __restrict__ W1,
                                            const float* __restrict__ b1,
                                            const float* __restrict__ dinv, int N,
                                            float* __restrict__ y1g) {
  __shared__ float W[16 * 32];
  __shared__ float bb[32];
  int tid = threadIdx.x;
  for (int i = tid; i < 512; i += BLK) W[i] = W1[i];
  if (tid < 32) bb[tid] = b1[tid];
  __syncthreads();
  int t = blockIdx.x * BLK + tid;
  int n = t >> 3, ch = t & 7;
  if (n >= N) return;
  const float* sr = s1 + (size_t)n * 16;
  float x[16];
#pragma unroll
  for (int k = 0; k < 16; ++k) x[k] = sr[k];
  int f0 = ch * 4;
  float a0 = bb[f0], a1 = bb[f0 + 1], a2 = bb[f0 + 2], a3 = bb[f0 + 3];
#pragma unroll
  for (int k = 0; k < 16; ++k) {
    float xv = x[k];
    const float* wr = &W[k * 32 + f0];
    a0 += xv * wr[0]; a1 += xv * wr[1]; a2 += xv * wr[2]; a3 += xv * wr[3];
  }
  float d = dinv[n];
  float4 o;
  o.x = fmaxf(a0, 0.f) * d;
  o.y = fmaxf(a1, 0.f) * d;
  o.z = fmaxf(a2, 0.f) * d;
  o.w = fmaxf(a3, 0.f) * d;
  *(float4*)(y1g + (size_t)n * 32 + f0) = o;
}

// s2[c] = dinv[c]*(sum y1g[r] + y1g[c]); pooled directly into P[batch[c]]
__global__ __launch_bounds__(BLK) void k_agg2(const float* __restrict__ y1g,
                                              const int* __restrict__ col_ptr,
                                              const int* __restrict__ edge_row,
                                              const float* __restrict__ dinv,
                                              const int* __restrict__ batch, int N,
                                              float* __restrict__ P) {
  int t = blockIdx.x * BLK + threadIdx.x;
  int n = t >> 3, ch = t & 7;
  if (n >= N) return;
  int off = ch * 4;
  float4 acc = *(const float4*)(y1g + (size_t)n * 32 + off);
  int beg = col_ptr[n], end = col_ptr[n + 1];
  for (int i = beg; i < end; ++i) {
    int r = edge_row[i];
    float4 v = *(const float4*)(y1g + (size_t)r * 32 + off);
    acc.x += v.x; acc.y += v.y; acc.z += v.z; acc.w += v.w;
  }
  float d = dinv[n];
  float* pb = P + (size_t)batch[n] * 32 + off;
  atomicAdd(pb + 0, acc.x * d);
  atomicAdd(pb + 1, acc.y * d);
  atomicAdd(pb + 2, acc.z * d);
  atomicAdd(pb + 3, acc.w * d);
}

// out[g] = P[g] @ W2 + cnt[g] * b2   (256 blocks x 64 threads)
__global__ __launch_bounds__(64) void k_final(const float* __restrict__ P,
                                              const int* __restrict__ cnt,
                                              const float* __restrict__ W2,
                                              const float* __restrict__ b2,
                                              float* __restrict__ out) {
  int g = blockIdx.x;
  int f = threadIdx.x;
  __shared__ float pr[32];
  if (f < 32) pr[f] = P[(size_t)g * 32 + f];
  __syncthreads();
  if (f < 41) {
    float acc = (float)cnt[g] * b2[f];
#pragma unroll
    for (int k = 0; k < 32; ++k) acc += pr[k] * W2[k * 41 + f];
    out[(size_t)g * 41 + f] = acc;
  }
}

extern "C" void kernel_launch(void* const* d_in, const int* in_sizes, int n_in,
                              void* d_out, int out_size, void* d_ws, size_t ws_size,
                              hipStream_t stream) {
  const int* x_ids = (const int*)d_in[0];
  const int* edge_index = (const int*)d_in[1];
  const int* batch = (const int*)d_in[2];
  const float* emb = (const float*)d_in[3];
  const float* W1 = (const float*)d_in[4];
  const float* b1 = (const float*)d_in[5];
  const float* W2 = (const float*)d_in[6];
  const float* b2 = (const float*)d_in[7];
  float* out = (float*)d_out;

  const int N = in_sizes[0];
  const int E = in_sizes[1] / 2;
  const int G = out_size / 41;
  const int* row = edge_index;
  const int* col = edge_index + E;
  const int nbkt = (N + BKT - 1) >> BKT_SHIFT;

  char* ws = (char*)d_ws;
  size_t off = 0;
  auto alloc = [&](size_t bytes) -> char* {
    char* p = ws + off;
    off += (bytes + 255) & ~(size_t)255;
    return p;
  };
  int* bcnt = (int*)alloc((size_t)MAXBKT * 4);
  int* bucket_off = (int*)alloc(((size_t)MAXBKT + 1) * 4);
  int* bcursor = (int*)alloc((size_t)MAXBKT * 4);
  int* bpacked = (int*)alloc((size_t)E * 4);
  int* edge_row = (int*)alloc((size_t)E * 4);
  int* col_ptr = (int*)alloc(((size_t)N + 1) * 4);
  float* dinv = (float*)alloc((size_t)N * 4);
  float* ag1 = (float*)alloc((size_t)N * 16 * 4);
  float* s1 = (float*)alloc((size_t)N * 16 * 4);
  float* y1g = (float*)alloc((size_t)N * 32 * 4);
  float* P = (float*)alloc((size_t)G * 32 * 4);
  int* cnt = (int*)alloc((size_t)G * 4);
  (void)ws_size; (void)n_in;

  hipMemsetAsync(bcnt, 0, (size_t)MAXBKT * 4, stream);
  hipMemsetAsync(P, 0, (size_t)G * 32 * 4, stream);
  hipMemsetAsync(cnt, 0, (size_t)G * 4, stream);

  k_bcount<<<(E + BLK - 1) / BLK, BLK, 0, stream>>>(col, E, bcnt);
  k_bscan<<<1, BLK, 0, stream>>>(bcnt, bucket_off, bcursor);
  k_bfill<<<(E + BLK - 1) / BLK, BLK, 0, stream>>>(row, col, E, bcursor, bpacked);
  k_build<<<nbkt, BLK, 0, stream>>>(bpacked, bucket_off, N, E, col_ptr, dinv, edge_row);
  k_prep<<<(N * 4 + BLK - 1) / BLK, BLK, 0, stream>>>(x_ids, batch, emb, dinv, N, ag1, cnt);
  k_agg1<<<(N * 4 + BLK - 1) / BLK, BLK, 0, stream>>>(ag1, col_ptr, edge_row, dinv, N, s1);
  k_t1<<<(N * 8 + BLK - 1) / BLK, BLK, 0, stream>>>(s1, W1, b1, dinv, N, y1g);
  k_agg2<<<(N * 8 + BLK - 1) / BLK, BLK, 0, stream>>>(y1g, col_ptr, edge_row, dinv, batch, N, P);
  k_final<<<G, 64, 0, stream>>>(P, cnt, W2, b2, out);
}

// Round 3
// 363.747 us; speedup vs baseline: 5.4704x; 5.4704x over previous
//
#include <hip/hip_runtime.h>

// 2-layer GCN, restructured:
//   ag1[n]  = emb[x_ids[n]] * dinv[n]                       (16f)
//   s1[c]   = dinv[c] * (sum_{r->c} ag1[r] + ag1[c])        (16f)  [CSR gather]
//   y1g[n]  = relu(s1[n] @ W1 + b1) * dinv[n]               (32f)
//   s2[c]   = dinv[c] * (sum_{r->c} y1g[r] + y1g[c])        (32f)  [CSR gather]
//   out[g]  = (sum_{batch==g} s2) @ W2 + cnt[g]*b2          (fused pool+GEMV)
//
// CSR build: partitioned counting sort. R1/R2 lesson: (a) global atomics on
// few addresses serialize (~200us/M ops); (b) scattered 4B stores write back
// ~empty 64B lines (16x amplification). Here every global store lands in a
// per-(bucket,block) segment written densely by ONE block -> full lines, and
// the only atomics are LDS-local.

constexpr int BLK = 256;
constexpr int EPB = 8192;          // edges per block in hist/scatter
constexpr int BSH = 10;            // 1024 nodes per bucket
constexpr int BKTN = 1 << BSH;

// per-block LDS histogram of col buckets
__global__ __launch_bounds__(BLK) void k_hist(const int* __restrict__ col, int E,
                                              int nbkt, int nblk,
                                              int* __restrict__ hist) {
  __shared__ int h[1024];
  int tid = threadIdx.x, blk = blockIdx.x;
  for (int i = tid; i < nbkt; i += BLK) h[i] = 0;
  __syncthreads();
  int e0 = blk * EPB, e1 = min(E, e0 + EPB);
  for (int e = e0 + tid; e < e1; e += BLK) atomicAdd(&h[col[e] >> BSH], 1);
  __syncthreads();
  for (int b = tid; b < nbkt; b += BLK) hist[b * nblk + blk] = h[b];
}

// single-block exclusive scan of hist (bucket-major) -> off; bucket segment
// starts -> bucket_off
__global__ __launch_bounds__(1024) void k_gscan(const int* __restrict__ hist,
                                                int tot, int nblk, int nbkt, int E,
                                                int* __restrict__ off,
                                                int* __restrict__ bucket_off) {
  __shared__ int sd[1024];
  int tid = threadIdx.x;
  int C = (tot + 1023) >> 10;
  int lo = tid * C, hi = min(tot, lo + C);
  int sum = 0;
  for (int i = lo; i < hi; ++i) sum += hist[i];
  sd[tid] = sum;
  __syncthreads();
  for (int o = 1; o < 1024; o <<= 1) {
    int v = (tid >= o) ? sd[tid - o] : 0;
    __syncthreads();
    sd[tid] += v;
    __syncthreads();
  }
  int run = sd[tid] - sum;  // exclusive
  for (int i = lo; i < hi; ++i) {
    off[i] = run;
    if (i % nblk == 0) bucket_off[i / nblk] = run;
    run += hist[i];
  }
  if (tid == 0) bucket_off[nbkt] = E;
}

// scatter packed edges into bucket-major segments; all stores dense per block
__global__ __launch_bounds__(BLK) void k_scatter(const int* __restrict__ row,
                                                 const int* __restrict__ col, int E,
                                                 int nbkt, int nblk,
                                                 const int* __restrict__ off,
                                                 int* __restrict__ staging) {
  __shared__ int base[1024];
  __shared__ int cur[1024];
  int tid = threadIdx.x, blk = blockIdx.x;
  for (int b = tid; b < nbkt; b += BLK) {
    base[b] = off[b * nblk + blk];
    cur[b] = 0;
  }
  __syncthreads();
  int e0 = blk * EPB, e1 = min(E, e0 + EPB);
  for (int e = e0 + tid; e < e1; e += BLK) {
    int c = col[e];
    int b = c >> BSH;
    int rk = atomicAdd(&cur[b], 1);
    staging[base[b] + rk] = (row[e] << BSH) | (c & (BKTN - 1));
  }
}

// per-bucket (1024 nodes): LDS count -> scan -> col_ptr/dinv -> edge_row fill
__global__ __launch_bounds__(1024) void k_build(const int* __restrict__ staging,
                                                const int* __restrict__ bucket_off,
                                                int N, int E,
                                                int* __restrict__ col_ptr,
                                                float* __restrict__ dinv,
                                                int* __restrict__ edge_row) {
  __shared__ int cnt[BKTN];
  __shared__ int sc[BKTN];
  __shared__ int lcur[BKTN];
  int tid = threadIdx.x, b = blockIdx.x;
  int beg = bucket_off[b], end = bucket_off[b + 1];
  cnt[tid] = 0;
  __syncthreads();
  for (int i = beg + tid; i < end; i += 1024)
    atomicAdd(&cnt[staging[i] & (BKTN - 1)], 1);
  __syncthreads();
  int c = cnt[tid];
  sc[tid] = c;
  __syncthreads();
  for (int o = 1; o < BKTN; o <<= 1) {
    int v = (tid >= o) ? sc[tid - o] : 0;
    __syncthreads();
    sc[tid] += v;
    __syncthreads();
  }
  int node = (b << BSH) + tid;
  if (node < N) {
    int pos = beg + sc[tid] - c;
    col_ptr[node] = pos;
    lcur[tid] = pos;
    dinv[node] = rsqrtf((float)(c + 1));  // +1 self-loop
  }
  if (b == 0 && tid == 0) col_ptr[N] = E;
  __syncthreads();
  for (int i = beg + tid; i < end; i += 1024) {
    int p = staging[i];
    int pos = atomicAdd(&lcur[p & (BKTN - 1)], 1);
    edge_row[pos] = p >> BSH;
  }
}

// ag1[n] = emb[x_ids[n]] * dinv[n]
__global__ __launch_bounds__(BLK) void k_prep(const int* __restrict__ x_ids,
                                              const float* __restrict__ emb,
                                              const float* __restrict__ dinv, int N,
                                              float* __restrict__ ag1) {
  int t = blockIdx.x * BLK + threadIdx.x;
  int n = t >> 2, ch = t & 3;
  if (n >= N) return;
  float d = dinv[n];
  float4 v = *(const float4*)(emb + (size_t)x_ids[n] * 16 + ch * 4);
  v.x *= d; v.y *= d; v.z *= d; v.w *= d;
  *(float4*)(ag1 + (size_t)n * 16 + ch * 4) = v;
}

// s1[c] = dinv[c] * (sum ag1[r] + ag1[c]); 4 lanes/node, float4 each
__global__ __launch_bounds__(BLK) void k_agg1(const float* __restrict__ ag1,
                                              const int* __restrict__ col_ptr,
                                              const int* __restrict__ edge_row,
                                              const float* __restrict__ dinv, int N,
                                              float* __restrict__ s1) {
  int t = blockIdx.x * BLK + threadIdx.x;
  int n = t >> 2, ch = t & 3;
  if (n >= N) return;
  int off = ch * 4;
  float4 acc = *(const float4*)(ag1 + (size_t)n * 16 + off);
  int beg = col_ptr[n], end = col_ptr[n + 1];
  for (int i = beg; i < end; ++i) {
    int r = edge_row[i];
    float4 v = *(const float4*)(ag1 + (size_t)r * 16 + off);
    acc.x += v.x; acc.y += v.y; acc.z += v.z; acc.w += v.w;
  }
  float d = dinv[n];
  acc.x *= d; acc.y *= d; acc.z *= d; acc.w *= d;
  *(float4*)(s1 + (size_t)n * 16 + off) = acc;
}

// y1g[n] = relu(s1[n] @ W1 + b1) * dinv[n]; 8 lanes/node, 4 outs each
__global__ __launch_bounds__(BLK) void k_t1(const float* __restrict__ s1,
                                            const float* __restrict__ W1,
                                            const float* __restrict__ b1,
                                            const float* __restrict__ dinv, int N,
                                            float* __restrict__ y1g) {
  __shared__ float W[16 * 32];
  __shared__ float bb[32];
  int tid = threadIdx.x;
  for (int i = tid; i < 512; i += BLK) W[i] = W1[i];
  if (tid < 32) bb[tid] = b1[tid];
  __syncthreads();
  int t = blockIdx.x * BLK + tid;
  int n = t >> 3, ch = t & 7;
  if (n >= N) return;
  const float* sr = s1 + (size_t)n * 16;
  float x[16];
#pragma unroll
  for (int k = 0; k < 16; ++k) x[k] = sr[k];
  int f0 = ch * 4;
  float a0 = bb[f0], a1 = bb[f0 + 1], a2 = bb[f0 + 2], a3 = bb[f0 + 3];
#pragma unroll
  for (int k = 0; k < 16; ++k) {
    float xv = x[k];
    const float* wr = &W[k * 32 + f0];
    a0 += xv * wr[0]; a1 += xv * wr[1]; a2 += xv * wr[2]; a3 += xv * wr[3];
  }
  float d = dinv[n];
  float4 o;
  o.x = fmaxf(a0, 0.f) * d;
  o.y = fmaxf(a1, 0.f) * d;
  o.z = fmaxf(a2, 0.f) * d;
  o.w = fmaxf(a3, 0.f) * d;
  *(float4*)(y1g + (size_t)n * 32 + f0) = o;
}

// s2[c] = dinv[c]*(sum y1g[r] + y1g[c]); plain store (no atomics)
__global__ __launch_bounds__(BLK) void k_agg2(const float* __restrict__ y1g,
                                              const int* __restrict__ col_ptr,
                                              const int* __restrict__ edge_row,
                                              const float* __restrict__ dinv, int N,
                                              float* __restrict__ s2) {
  int t = blockIdx.x * BLK + threadIdx.x;
  int n = t >> 3, ch = t & 7;
  if (n >= N) return;
  int off = ch * 4;
  float4 acc = *(const float4*)(y1g + (size_t)n * 32 + off);
  int beg = col_ptr[n], end = col_ptr[n + 1];
  for (int i = beg; i < end; ++i) {
    int r = edge_row[i];
    float4 v = *(const float4*)(y1g + (size_t)r * 32 + off);
    acc.x += v.x; acc.y += v.y; acc.z += v.z; acc.w += v.w;
  }
  float d = dinv[n];
  acc.x *= d; acc.y *= d; acc.z *= d; acc.w *= d;
  *(float4*)(s2 + (size_t)n * 32 + off) = acc;
}

// batch is SORTED: block g binary-searches its node range, sums s2 rows,
// then out[g] = psum @ W2 + cnt*b2. No atomics.
__global__ __launch_bounds__(BLK) void k_pool(const float* __restrict__ s2,
                                              const int* __restrict__ batch, int N,
                                              const float* __restrict__ W2,
                                              const float* __restrict__ b2,
                                              float* __restrict__ out) {
  __shared__ int se[2];
  __shared__ float sd[BLK];
  int g = blockIdx.x, tid = threadIdx.x;
  if (tid < 2) {
    int v = g + tid;
    int lo = 0, hi = N;
    while (lo < hi) {
      int mid = (lo + hi) >> 1;
      if (batch[mid] < v) lo = mid + 1; else hi = mid;
    }
    se[tid] = lo;
  }
  __syncthreads();
  int start = se[0], end = se[1];
  int f = tid & 31, grp = tid >> 5;
  float acc = 0.f;
  for (int n = start + grp; n < end; n += 8) acc += s2[(size_t)n * 32 + f];
  sd[tid] = acc;
  __syncthreads();
  if (tid < 128) sd[tid] += sd[tid + 128];
  __syncthreads();
  if (tid < 64) sd[tid] += sd[tid + 64];
  __syncthreads();
  if (tid < 32) sd[tid] += sd[tid + 32];
  __syncthreads();
  if (tid < 41) {
    float o = (float)(end - start) * b2[tid];
#pragma unroll
    for (int k = 0; k < 32; ++k) o += sd[k] * W2[k * 41 + tid];
    out[(size_t)g * 41 + tid] = o;
  }
}

extern "C" void kernel_launch(void* const* d_in, const int* in_sizes, int n_in,
                              void* d_out, int out_size, void* d_ws, size_t ws_size,
                              hipStream_t stream) {
  const int* x_ids = (const int*)d_in[0];
  const int* edge_index = (const int*)d_in[1];
  const int* batch = (const int*)d_in[2];
  const float* emb = (const float*)d_in[3];
  const float* W1 = (const float*)d_in[4];
  const float* b1 = (const float*)d_in[5];
  const float* W2 = (const float*)d_in[6];
  const float* b2 = (const float*)d_in[7];
  float* out = (float*)d_out;

  const int N = in_sizes[0];
  const int E = in_sizes[1] / 2;
  const int G = out_size / 41;
  const int* row = edge_index;
  const int* col = edge_index + E;

  const int nbkt = (N + BKTN - 1) >> BSH;       // 98
  const int nblk = (E + EPB - 1) / EPB;         // 391
  const int tot = nbkt * nblk;

  char* ws = (char*)d_ws;
  size_t woff = 0;
  auto alloc = [&](size_t bytes) -> char* {
    char* p = ws + woff;
    woff += (bytes + 255) & ~(size_t)255;
    return p;
  };
  size_t stage_bytes = (size_t)E * 4;
  size_t s2_bytes = (size_t)N * 32 * 4;
  int* staging = (int*)alloc(stage_bytes > s2_bytes ? stage_bytes : s2_bytes);
  int* edge_row = (int*)alloc((size_t)E * 4);
  int* col_ptr = (int*)alloc(((size_t)N + 1) * 4);
  float* dinv = (float*)alloc((size_t)N * 4);
  float* ag1 = (float*)alloc((size_t)N * 16 * 4);
  float* s1 = (float*)alloc((size_t)N * 16 * 4);
  float* y1g = (float*)alloc((size_t)N * 32 * 4);
  int* hist = (int*)alloc((size_t)tot * 4);
  int* off = (int*)alloc((size_t)tot * 4);
  int* bucket_off = (int*)alloc(((size_t)nbkt + 1) * 4);
  float* s2 = (float*)staging;  // staging dead after k_build
  (void)ws_size; (void)n_in;

  k_hist<<<nblk, BLK, 0, stream>>>(col, E, nbkt, nblk, hist);
  k_gscan<<<1, 1024, 0, stream>>>(hist, tot, nblk, nbkt, E, off, bucket_off);
  k_scatter<<<nblk, BLK, 0, stream>>>(row, col, E, nbkt, nblk, off, staging);
  k_build<<<nbkt, 1024, 0, stream>>>(staging, bucket_off, N, E, col_ptr, dinv, edge_row);
  k_prep<<<(N * 4 + BLK - 1) / BLK, BLK, 0, stream>>>(x_ids, emb, dinv, N, ag1);
  k_agg1<<<(N * 4 + BLK - 1) / BLK, BLK, 0, stream>>>(ag1, col_ptr, edge_row, dinv, N, s1);
  k_t1<<<(N * 8 + BLK - 1) / BLK, BLK, 0, stream>>>(s1, W1, b1, dinv, N, y1g);
  k_agg2<<<(N * 8 + BLK - 1) / BLK, BLK, 0, stream>>>(y1g, col_ptr, edge_row, dinv, N, s2);
  k_pool<<<G, BLK, 0, stream>>>(s2, batch, N, W2, b2, out);
}